// Round 1
// baseline (83.080 us; speedup 1.0000x reference)
//
#include <hip/hip_runtime.h>
#include <math.h>

namespace {
constexpr int K_ = 9;
constexpr int H_ = 5;
constexpr int NSHELL_ = 321;   // H*(K-1)^2 + 1
constexpr int NPTS_ = 200000;
constexpr int B_ = 512;
constexpr float C_COEF_ = 0.49996397161691486f;
constexpr float LAM0_ = 1.0f;
constexpr float EPS_ = 1e-8f;
constexpr float HLOGK_ = 10.986122886681098f;  // H*ln(K)
constexpr float M_F = 59049.0f;                // K^H
}

// Kernel 1: base copy lam -> out[1..N], rho -> out[1+N..1+2N]
__global__ __launch_bounds__(256) void copy_base(const float* __restrict__ lam,
                                                 const float* __restrict__ rho,
                                                 float* __restrict__ out) {
    int i = blockIdx.x * 256 + threadIdx.x;
    if (i < NPTS_) {
        out[1 + i] = lam[i];
        out[1 + NPTS_ + i] = rho[i];
    }
}

// Kernel 2: one wave (64 lanes) per batch row b.
// Computes p_shell via 5-fold convolution of per-factor shell distributions,
// then all per-row scalars. Writes {lam_b*nll, lam_new_b, rho_new_b} to ws.
__global__ __launch_bounds__(64) void per_b(const float* __restrict__ logits,
                                            const int* __restrict__ idx,
                                            const int* __restrict__ Y,
                                            const float* __restrict__ lam,
                                            const float* __restrict__ rho,
                                            float* __restrict__ ws) {
    __shared__ float logp[H_][K_];
    __shared__ float p[H_][K_];
    __shared__ float logz[K_];
    __shared__ int ysh[H_];
    __shared__ float acc[2][NSHELL_];

    const int b = blockIdx.x;
    const int lane = threadIdx.x;
    const int id = idx[b];

    if (lane < H_) ysh[lane] = Y[id * H_ + lane];
    if (lane < K_) {
        // z[i] = sum_j exp(-C*(i-j)^2), same summation order as reference
        float z = 0.f;
        for (int j = 0; j < K_; ++j) {
            float d = (float)(lane - j);
            z += expf(-C_COEF_ * d * d);
        }
        logz[lane] = logf(z);
    }
    for (int s = lane; s < NSHELL_; s += 64) acc[0][s] = 0.f;
    if (lane < H_) {
        // log_softmax for factor h = lane
        const float* lg = logits + (b * H_ + lane) * K_;
        float x[K_];
        float m = -1e30f;
        for (int k = 0; k < K_; ++k) { x[k] = lg[k]; m = fmaxf(m, x[k]); }
        float se = 0.f;
        for (int k = 0; k < K_; ++k) se += expf(x[k] - m);
        float ls = m + logf(se);
        for (int k = 0; k < K_; ++k) {
            float lp = x[k] - ls;
            logp[lane][k] = lp;
            p[lane][k] = expf(lp);
        }
    }
    __syncthreads();

    // init convolution with factor h=0 (single-thread scatter, <=9 entries)
    if (lane == 0) {
        int y0 = ysh[0];
        for (int c = 0; c < K_; ++c) {
            int o = c - y0; o *= o;
            acc[0][o] += p[0][c];
        }
    }
    __syncthreads();

    // convolve factors h=1..4 (gather form: no conflicts, no atomics)
    int cur = 0;
    for (int h = 1; h < H_; ++h) {
        const int yh = ysh[h];
        float w[K_];
        int off[K_];
        for (int c = 0; c < K_; ++c) { int o = c - yh; off[c] = o * o; w[c] = p[h][c]; }
        for (int s = lane; s < NSHELL_; s += 64) {
            float v = 0.f;
            for (int c = 0; c < K_; ++c) {
                int sp = s - off[c];
                if (sp >= 0) v += w[c] * acc[cur][sp];
            }
            acc[cur ^ 1][s] = v;
        }
        cur ^= 1;
        __syncthreads();
    }

    // per-row scalars
    float logzsum = 0.f, logp_t = 0.f;
    for (int h = 0; h < H_; ++h) {
        int yh = ysh[h];
        logzsum += logz[yh];
        logp_t += logp[h][yh];
    }
    const float Z_mode = expf(logzsum);
    const float A = M_F / Z_mode;  // Kpi_t
    const float rho_b = rho[id];
    const float lam_b = lam[id];
    const float srho = (rho_b == 0.f) ? 1.f : rho_b;

    // shell sums (only der[0], der[1] are consumed downstream)
    float k1 = 0.f, k2 = 0.f, dr1 = 0.f, dr2 = 0.f;
    for (int s = lane; s < NSHELL_; s += 64) {
        float ps = acc[cur][s];
        float Kpi = A * expf(-C_COEF_ * (float)s);
        k1 += ps * Kpi;
        k2 += ps * Kpi * Kpi;
        float lS = log1pf(srho * (Kpi - 1.f));
        float ratio = -expm1f(-lS) / srho;
        dr1 += ps * ratio;
        dr2 += ps * ratio * ratio;
    }
    for (int o = 32; o > 0; o >>= 1) {
        k1 += __shfl_down(k1, o);
        k2 += __shfl_down(k2, o);
        dr1 += __shfl_down(dr1, o);
        dr2 += __shfl_down(dr2, o);
    }

    if (lane == 0) {
        float d0, d1;
        if (rho_b == 0.f) { d0 = k1 - 1.f; d1 = k2 - 2.f * k1 + 1.f; }
        else             { d0 = dr1;      d1 = dr2; }
        float S_t = 1.f + rho_b * (A - 1.f);
        float nll = -(logp_t + logf(S_t + EPS_));
        float rho_new = rho_b - d0 / (d1 + EPS_);
        rho_new = fminf(fmaxf(rho_new, 0.f), 1.f);
        float lam_tgt = LAM0_ * HLOGK_ / (nll + EPS_);
        float lam_new = 0.9f * lam_b + 0.1f * fminf(lam_tgt, LAM0_);
        lam_new = fminf(fmaxf(lam_new, LAM0_ * 0.5f), LAM0_);
        ws[b] = lam_b * nll;
        ws[B_ + b] = lam_new;
        ws[2 * B_ + b] = rho_new;
    }
}

// Kernel 3: deterministic loss reduction + last-occurrence-wins scatter
__global__ __launch_bounds__(512) void finalize(const int* __restrict__ idx,
                                                const float* __restrict__ ws,
                                                float* __restrict__ out) {
    __shared__ float red[B_];
    const int t = threadIdx.x;
    red[t] = ws[t];
    __syncthreads();
    for (int s = 256; s > 0; s >>= 1) {
        if (t < s) red[t] += red[t + s];
        __syncthreads();
    }
    if (t == 0) out[0] = red[0] / (float)B_;

    const int my = idx[t];
    bool keep = true;
    for (int b2 = t + 1; b2 < B_; ++b2) {
        if (idx[b2] == my) { keep = false; break; }
    }
    if (keep) {
        out[1 + my]          = ws[B_ + t];
        out[1 + NPTS_ + my]  = ws[2 * B_ + t];
    }
}

extern "C" void kernel_launch(void* const* d_in, const int* in_sizes, int n_in,
                              void* d_out, int out_size, void* d_ws, size_t ws_size,
                              hipStream_t stream) {
    const float* logits = (const float*)d_in[0];  // (B, H, K) fp32
    const int*   idx    = (const int*)d_in[1];    // (B,)
    const int*   Y      = (const int*)d_in[2];    // (N, H)
    const float* lam    = (const float*)d_in[3];  // (N,)
    const float* rho    = (const float*)d_in[4];  // (N,)
    float* out = (float*)d_out;                   // [loss | lam_new(N) | rho_new(N)]
    float* ws  = (float*)d_ws;                    // [wn(B) | lam_new_b(B) | rho_new_b(B)]

    copy_base<<<(NPTS_ + 255) / 256, 256, 0, stream>>>(lam, rho, out);
    per_b<<<B_, 64, 0, stream>>>(logits, idx, Y, lam, rho, ws);
    finalize<<<1, B_, 0, stream>>>(idx, ws, out);
}

// Round 3
// 29.768 us; speedup vs baseline: 2.7909x; 2.7909x over previous
//
#include <hip/hip_runtime.h>
#include <math.h>

namespace {
constexpr int K_ = 9;
constexpr int H_ = 5;
constexpr int NSHELL_ = 321;   // H*(K-1)^2 + 1
constexpr int NPTS_ = 200000;
constexpr int B_ = 512;
constexpr float C_COEF_ = 0.49996397161691486f;
constexpr float LAM0_ = 1.0f;
constexpr float EPS_ = 1e-8f;
constexpr float HLOGK_ = 10.986122886681098f;  // H*ln(K)
constexpr float M_F = 59049.0f;                // K^H
}

// Kernel 1: base copy lam -> out[1..N], rho -> out[1+N..1+2N]
__global__ __launch_bounds__(256) void copy_base(const float* __restrict__ lam,
                                                 const float* __restrict__ rho,
                                                 float* __restrict__ out) {
    int i = blockIdx.x * 256 + threadIdx.x;
    if (i < NPTS_) {
        out[1 + i] = lam[i];
        out[1 + NPTS_ + i] = rho[i];
    }
}

// Kernel 2: one wave (64 lanes) per batch row b.
// Computes p_shell via 5-fold convolution of per-factor shell distributions,
// then all per-row scalars. Writes lam_b*nll to ws[b] and — iff this block is
// the LAST occurrence of its idx value — writes lam_new/rho_new directly to
// out. Winner selection depends only on the immutable idx input, so the
// scatter is race-free and bit-deterministic across replays.
__global__ __launch_bounds__(64) void per_b(const float* __restrict__ logits,
                                            const int* __restrict__ idx,
                                            const int* __restrict__ Y,
                                            const float* __restrict__ lam,
                                            const float* __restrict__ rho,
                                            float* __restrict__ ws,
                                            float* __restrict__ out) {
    __shared__ float logp[H_][K_];
    __shared__ float p[H_][K_];
    __shared__ float logz[K_];
    __shared__ int ysh[H_];
    __shared__ float acc[2][NSHELL_];

    const int b = blockIdx.x;
    const int lane = threadIdx.x;
    const int id = idx[b];

    if (lane < H_) ysh[lane] = Y[id * H_ + lane];
    if (lane < K_) {
        // z[i] = sum_j exp(-C*(i-j)^2), same summation order as reference
        float z = 0.f;
        for (int j = 0; j < K_; ++j) {
            float d = (float)(lane - j);
            z += expf(-C_COEF_ * d * d);
        }
        logz[lane] = logf(z);
    }
    for (int s = lane; s < NSHELL_; s += 64) acc[0][s] = 0.f;
    if (lane < H_) {
        // log_softmax for factor h = lane
        const float* lg = logits + (b * H_ + lane) * K_;
        float x[K_];
        float m = -1e30f;
        for (int k = 0; k < K_; ++k) { x[k] = lg[k]; m = fmaxf(m, x[k]); }
        float se = 0.f;
        for (int k = 0; k < K_; ++k) se += expf(x[k] - m);
        float ls = m + logf(se);
        for (int k = 0; k < K_; ++k) {
            float lp = x[k] - ls;
            logp[lane][k] = lp;
            p[lane][k] = expf(lp);
        }
    }

    // last-occurrence test: does any b2 > b share our idx value?
    // B_ = 512 = 8 strides of 64 lanes; coalesced, L2-resident.
    bool later_dup = false;
    for (int j = 0; j < 8; ++j) {
        int pos = j * 64 + lane;
        int v = idx[pos];
        later_dup |= (pos > b) && (v == id);
    }
    const bool keep = (__any(later_dup ? 1 : 0) == 0);

    __syncthreads();

    // init convolution with factor h=0 (single-thread scatter, <=9 entries)
    if (lane == 0) {
        int y0 = ysh[0];
        for (int c = 0; c < K_; ++c) {
            int o = c - y0; o *= o;
            acc[0][o] += p[0][c];
        }
    }
    __syncthreads();

    // convolve factors h=1..4 (gather form: no conflicts, no atomics)
    int cur = 0;
    for (int h = 1; h < H_; ++h) {
        const int yh = ysh[h];
        float w[K_];
        int off[K_];
        for (int c = 0; c < K_; ++c) { int o = c - yh; off[c] = o * o; w[c] = p[h][c]; }
        for (int s = lane; s < NSHELL_; s += 64) {
            float v = 0.f;
            for (int c = 0; c < K_; ++c) {
                int sp = s - off[c];
                if (sp >= 0) v += w[c] * acc[cur][sp];
            }
            acc[cur ^ 1][s] = v;
        }
        cur ^= 1;
        __syncthreads();
    }

    // per-row scalars
    float logzsum = 0.f, logp_t = 0.f;
    for (int h = 0; h < H_; ++h) {
        int yh = ysh[h];
        logzsum += logz[yh];
        logp_t += logp[h][yh];
    }
    const float Z_mode = expf(logzsum);
    const float A = M_F / Z_mode;  // Kpi_t
    const float rho_b = rho[id];
    const float lam_b = lam[id];
    const float srho = (rho_b == 0.f) ? 1.f : rho_b;

    // shell sums (only der[0], der[1] are consumed downstream)
    float k1 = 0.f, k2 = 0.f, dr1 = 0.f, dr2 = 0.f;
    for (int s = lane; s < NSHELL_; s += 64) {
        float ps = acc[cur][s];
        float Kpi = A * expf(-C_COEF_ * (float)s);
        k1 += ps * Kpi;
        k2 += ps * Kpi * Kpi;
        float lS = log1pf(srho * (Kpi - 1.f));
        float ratio = -expm1f(-lS) / srho;
        dr1 += ps * ratio;
        dr2 += ps * ratio * ratio;
    }
    for (int o = 32; o > 0; o >>= 1) {
        k1 += __shfl_down(k1, o);
        k2 += __shfl_down(k2, o);
        dr1 += __shfl_down(dr1, o);
        dr2 += __shfl_down(dr2, o);
    }

    if (lane == 0) {
        float d0, d1;
        if (rho_b == 0.f) { d0 = k1 - 1.f; d1 = k2 - 2.f * k1 + 1.f; }
        else             { d0 = dr1;      d1 = dr2; }
        float S_t = 1.f + rho_b * (A - 1.f);
        float nll = -(logp_t + logf(S_t + EPS_));
        float rho_new = rho_b - d0 / (d1 + EPS_);
        rho_new = fminf(fmaxf(rho_new, 0.f), 1.f);
        float lam_tgt = LAM0_ * HLOGK_ / (nll + EPS_);
        float lam_new = 0.9f * lam_b + 0.1f * fminf(lam_tgt, LAM0_);
        lam_new = fminf(fmaxf(lam_new, LAM0_ * 0.5f), LAM0_);
        ws[b] = lam_b * nll;
        if (keep) {
            out[1 + id]          = lam_new;
            out[1 + NPTS_ + id]  = rho_new;
        }
    }
}

// Kernel 3: deterministic loss tree-reduction only.
__global__ __launch_bounds__(512) void finalize(const float* __restrict__ ws,
                                                float* __restrict__ out) {
    __shared__ float red[B_];
    const int t = threadIdx.x;
    red[t] = ws[t];
    __syncthreads();
    for (int s = 256; s > 0; s >>= 1) {
        if (t < s) red[t] += red[t + s];
        __syncthreads();
    }
    if (t == 0) out[0] = red[0] / (float)B_;
}

extern "C" void kernel_launch(void* const* d_in, const int* in_sizes, int n_in,
                              void* d_out, int out_size, void* d_ws, size_t ws_size,
                              hipStream_t stream) {
    const float* logits = (const float*)d_in[0];  // (B, H, K) fp32
    const int*   idx    = (const int*)d_in[1];    // (B,)
    const int*   Y      = (const int*)d_in[2];    // (N, H)
    const float* lam    = (const float*)d_in[3];  // (N,)
    const float* rho    = (const float*)d_in[4];  // (N,)
    float* out = (float*)d_out;                   // [loss | lam_new(N) | rho_new(N)]
    float* ws  = (float*)d_ws;                    // [wn(B)]

    copy_base<<<(NPTS_ + 255) / 256, 256, 0, stream>>>(lam, rho, out);
    per_b<<<B_, 64, 0, stream>>>(logits, idx, Y, lam, rho, ws, out);
    finalize<<<1, B_, 0, stream>>>(ws, out);
}